// Round 1
// baseline (447.233 us; speedup 1.0000x reference)
//
#include <hip/hip_runtime.h>

// Nearest-qpoint quantize: out[i] = nearest of 16 sorted qpoints to x[i],
// ties to the LEFT (lower) qpoint, bit-exact vs the numpy reference:
//   idx = searchsorted(q, x); lo = q[clip(idx-1,0,15)]; hi = q[clip(idx,0,15)]
//   out = |x-lo| <= |x-hi| ? lo : hi
// lo = last q[k] <  x (or q[0] if none)   -> ascending cndmask chain
// hi = first q[k] >= x (or q[15] if none) -> descending cndmask chain

__device__ __forceinline__ float quant1(float xv, const float qp[16]) {
    float hi = qp[15];
#pragma unroll
    for (int k = 14; k >= 0; --k) hi = (qp[k] >= xv) ? qp[k] : hi;
    float lo = qp[0];
#pragma unroll
    for (int k = 1; k < 16; ++k) lo = (qp[k] < xv) ? qp[k] : lo;
    return (fabsf(xv - lo) <= fabsf(xv - hi)) ? lo : hi;
}

__global__ __launch_bounds__(256) void qquant_vec4(
    const float4* __restrict__ x, const float* __restrict__ q,
    float4* __restrict__ out, int n4) {
    int i = blockIdx.x * blockDim.x + threadIdx.x;
    if (i >= n4) return;

    float qp[16];
#pragma unroll
    for (int k = 0; k < 16; ++k) qp[k] = q[k];  // uniform -> SGPRs

    float4 v = x[i];
    float4 r;
    r.x = quant1(v.x, qp);
    r.y = quant1(v.y, qp);
    r.z = quant1(v.z, qp);
    r.w = quant1(v.w, qp);
    out[i] = r;
}

__global__ void qquant_tail(const float* __restrict__ x,
                            const float* __restrict__ q,
                            float* __restrict__ out, int start, int n) {
    int i = start + threadIdx.x;
    if (i >= n) return;
    float qp[16];
#pragma unroll
    for (int k = 0; k < 16; ++k) qp[k] = q[k];
    out[i] = quant1(x[i], qp);
}

extern "C" void kernel_launch(void* const* d_in, const int* in_sizes, int n_in,
                              void* d_out, int out_size, void* d_ws, size_t ws_size,
                              hipStream_t stream) {
    const float* x = (const float*)d_in[0];
    const float* q = (const float*)d_in[1];
    float* out = (float*)d_out;
    int n = in_sizes[0];

    int n4 = n >> 2;
    if (n4 > 0) {
        int blocks = (n4 + 255) / 256;
        qquant_vec4<<<blocks, 256, 0, stream>>>((const float4*)x, q,
                                                (float4*)out, n4);
    }
    int rem = n & 3;
    if (rem > 0) {  // host-side branch on constant sizes: graph-capture safe
        qquant_tail<<<1, 64, 0, stream>>>(x, q, out, n4 << 2, n);
    }
}

// Round 2
// 445.451 us; speedup vs baseline: 1.0040x; 1.0040x over previous
//
#include <hip/hip_runtime.h>

// Nearest-qpoint quantize, bit-exact vs numpy reference:
//   idx = searchsorted(q, x); lo = q[clip(idx-1,0,15)]; hi = q[clip(idx,0,15)]
//   out = |x-lo| <= |x-hi| ? lo : hi
//
// R1 change: the 16 qpoints are loaded with 4 float4 vector loads and forced
// into SGPRs via readfirstlane (R0 emitted 16 per-lane global_load_dword per
// thread -> VMEM-issue-bound at ~490us). Grid-stride loop amortizes the
// one-time q load over ~8 float4s per thread.

__device__ __forceinline__ float rfl(float v) {
    return __int_as_float(__builtin_amdgcn_readfirstlane(__float_as_int(v)));
}

__device__ __forceinline__ float quant1(float xv, const float qp[16]) {
    float hi = qp[15];
#pragma unroll
    for (int k = 14; k >= 0; --k) hi = (qp[k] >= xv) ? qp[k] : hi;
    float lo = qp[0];
#pragma unroll
    for (int k = 1; k < 16; ++k) lo = (qp[k] < xv) ? qp[k] : lo;
    return (fabsf(xv - lo) <= fabsf(xv - hi)) ? lo : hi;
}

__global__ __launch_bounds__(256) void qquant_vec4(
    const float4* __restrict__ x, const float* __restrict__ q,
    float4* __restrict__ out, int n4) {
    // One-time qpoint load: 4 VMEM ops, then pin to SGPRs.
    const float4* q4 = (const float4*)q;
    float4 q0 = q4[0], q1 = q4[1], q2 = q4[2], q3 = q4[3];
    float qp[16] = {rfl(q0.x), rfl(q0.y), rfl(q0.z), rfl(q0.w),
                    rfl(q1.x), rfl(q1.y), rfl(q1.z), rfl(q1.w),
                    rfl(q2.x), rfl(q2.y), rfl(q2.z), rfl(q2.w),
                    rfl(q3.x), rfl(q3.y), rfl(q3.z), rfl(q3.w)};

    int stride = gridDim.x * blockDim.x;
    for (int i = blockIdx.x * blockDim.x + threadIdx.x; i < n4; i += stride) {
        float4 v = x[i];
        float4 r;
        r.x = quant1(v.x, qp);
        r.y = quant1(v.y, qp);
        r.z = quant1(v.z, qp);
        r.w = quant1(v.w, qp);
        out[i] = r;
    }
}

__global__ void qquant_tail(const float* __restrict__ x,
                            const float* __restrict__ q,
                            float* __restrict__ out, int start, int n) {
    int i = start + threadIdx.x;
    if (i >= n) return;
    float qp[16];
#pragma unroll
    for (int k = 0; k < 16; ++k) qp[k] = q[k];
    out[i] = quant1(x[i], qp);
}

extern "C" void kernel_launch(void* const* d_in, const int* in_sizes, int n_in,
                              void* d_out, int out_size, void* d_ws, size_t ws_size,
                              hipStream_t stream) {
    const float* x = (const float*)d_in[0];
    const float* q = (const float*)d_in[1];
    float* out = (float*)d_out;
    int n = in_sizes[0];

    int n4 = n >> 2;
    if (n4 > 0) {
        // ~8 float4 per thread: 8192 blocks x 256 thr = 2.1M threads covers
        // 16.78M float4s. Cap at what's needed for small n.
        int blocks = (n4 + 255) / 256;
        if (blocks > 8192) blocks = 8192;
        qquant_vec4<<<blocks, 256, 0, stream>>>((const float4*)x, q,
                                                (float4*)out, n4);
    }
    int rem = n & 3;
    if (rem > 0) {  // host-side branch on constant sizes: graph-capture safe
        qquant_tail<<<1, 64, 0, stream>>>(x, q, out, n4 << 2, n);
    }
}